// Round 9
// baseline (244.281 us; speedup 1.0000x reference)
//
#include <hip/hip_runtime.h>

// LSTM forecast: B=1024, S=512, I=1, H=50.
// R9 = R8 (2-wave gate-split per batch, 2048 waves = 2/SIMD) with the
// register budget FORCED: amdgpu_waves_per_eu(2,2) (min AND max -> 256
// VGPR/wave budget) + asm pins on the weight registers. R8 ran at VGPR=48:
// the allocator spilled/remat'd the 50 weight regs every step, confounding
// the occupancy experiment (VALUBusy 54% x 1120cyc = 605 issue vs ~250
// expected). wave0: gates i,g + cell tail + h publish; wave1: gates f,o.

typedef _Float16 half2v __attribute__((ext_vector_type(2)));

#define LOG2E 1.44269504088896340736f
#define B_ 1024
#define S_ 512
#define H_ 50

__device__ __forceinline__ float rcp_(float x) { return __builtin_amdgcn_rcpf(x); }
__device__ __forceinline__ float ex2_(float x) { return __builtin_amdgcn_exp2f(x); }
__device__ __forceinline__ float fdot2_(unsigned hp, half2v w, float acc) {
    return __builtin_amdgcn_fdot2(__builtin_bit_cast(half2v, hp), w, acc, false);
}

// Pack W_hh into [gate][pair m][lane] f16-pairs, pre-scaled by activation
// log2 factors (i,f,o: -log2e ; g: +2*log2e). Also pre-scale W_ih and biases.
__global__ void lstm_pack(const float* __restrict__ W_ih, const float* __restrict__ W_hh,
                          const float* __restrict__ b_ih, const float* __restrict__ b_hh,
                          unsigned* __restrict__ wpk, float* __restrict__ wih_pk,
                          float* __restrict__ bias_pk)
{
    int tid = blockIdx.x * blockDim.x + threadIdx.x;
    int stride = blockDim.x * gridDim.x;
    for (int p = tid; p < 4 * 25 * 64; p += stride) {
        int j = p & 63;
        int m = (p >> 6) % 25;
        int g = p / (25 * 64);
        float s = (g == 2) ? (2.0f * LOG2E) : (-LOG2E);
        float a = 0.0f, bb = 0.0f;
        if (j < H_) {
            int row = g * H_ + j;
            a  = s * W_hh[row * H_ + 2 * m];
            bb = s * W_hh[row * H_ + 2 * m + 1];
        }
        half2v hv;
        hv.x = (_Float16)a;
        hv.y = (_Float16)bb;
        wpk[p] = __builtin_bit_cast(unsigned, hv);
    }
    for (int p = tid; p < 4 * 64; p += stride) {
        int j = p & 63;
        int g = p >> 6;
        float s = (g == 2) ? (2.0f * LOG2E) : (-LOG2E);
        float wi = 0.0f, bb = 0.0f;
        if (j < H_) {
            int row = g * H_ + j;
            wi = s * W_ih[row];
            bb = s * (b_ih[row] + b_hh[row]);
        }
        wih_pk[p] = wi;
        bias_pk[p] = bb;
    }
}

__global__
__attribute__((amdgpu_flat_work_group_size(128, 128)))
__attribute__((amdgpu_waves_per_eu(2, 2)))
void lstm_main(const float* __restrict__ x, const float* __restrict__ h0,
               const float* __restrict__ c0, const float* __restrict__ fc_w,
               const float* __restrict__ fc_b, const unsigned* __restrict__ wpk,
               const float* __restrict__ wih_pk, const float* __restrict__ bias_pk,
               float* __restrict__ out)
{
    const int b   = blockIdx.x;
    const int tid = threadIdx.x;
    const int j   = tid & 63;
    const int wid = tid >> 6;

    __shared__ unsigned hs16[32];   // packed f16x2 h-pairs, slot m = (h[2m],h[2m+1])
    __shared__ float2   sfso[64];   // wave1 -> wave0: (sigmoid(f), sigmoid(o)) per j

    // wave0 -> gates 0 (i) and 2 (g); wave1 -> gates 1 (f) and 3 (o)
    const int gA = wid;       // i / f  (sigmoid, scale -log2e folded)
    const int gB = wid + 2;   // g / o  (g: tanh, +2log2e; o: sigmoid, -log2e)

    half2v wA[25], wB[25];
    #pragma unroll
    for (int m = 0; m < 25; ++m) {
        wA[m] = __builtin_bit_cast(half2v, wpk[(gA * 25 + m) * 64 + j]);
        wB[m] = __builtin_bit_cast(half2v, wpk[(gB * 25 + m) * 64 + j]);
    }
    // Pin weights in VGPRs (R4-proven under sufficient budget; R8's VGPR=48
    // budget made the allocator remat these every step).
    #pragma unroll
    for (int m = 0; m < 25; ++m) {
        asm volatile("" : "+v"(wA[m]));
        asm volatile("" : "+v"(wB[m]));
    }
    float wihA = wih_pk[gA * 64 + j], wihB = wih_pk[gB * 64 + j];
    float bsA  = bias_pk[gA * 64 + j], bsB = bias_pk[gB * 64 + j];

    float h = (j < H_) ? h0[b * H_ + j] : 0.0f;
    float c = (j < H_) ? c0[b * H_ + j] : 0.0f;

    if (wid == 0) {
        // publish initial h-pairs: even lane 2m packs (h[2m], h[2m+1])
        int hn_ = __builtin_amdgcn_update_dpp(0, __builtin_bit_cast(int, h),
                                              0xB1, 0xF, 0xF, true);
        unsigned hpk = __builtin_bit_cast(unsigned,
            __builtin_amdgcn_cvt_pkrtz(h, __builtin_bit_cast(float, hn_)));
        if ((j & 1) == 0 && j < H_) hs16[j >> 1] = hpk;
    }
    __syncthreads();
    unsigned hp[25];
    #pragma unroll
    for (int m = 0; m < 25; ++m) hp[m] = hs16[m];

    const float* __restrict__ xrow = x + b * S_;
    float xt = xrow[0];

    for (int s = 0; s < S_; ++s) {
        float xt_n = xrow[s + 1 < S_ ? s + 1 : S_ - 1];

        // 2 gates x tree-split (13+12) = 4 independent fdot2 chains
        float aA1 = __builtin_fmaf(xt, wihA, bsA), aA2 = 0.0f;
        float aB1 = __builtin_fmaf(xt, wihB, bsB), aB2 = 0.0f;
        #pragma unroll
        for (int m = 0; m < 13; ++m) {
            aA1 = fdot2_(hp[m], wA[m], aA1);
            aB1 = fdot2_(hp[m], wB[m], aB1);
        }
        #pragma unroll
        for (int m = 13; m < 25; ++m) {
            aA2 = fdot2_(hp[m], wA[m], aA2);
            aB2 = fdot2_(hp[m], wB[m], aB2);
        }
        float aA = aA1 + aA2;   // w0: i-arg   w1: f-arg   (pre-scaled -log2e)
        float aB = aB1 + aB2;   // w0: g-arg(+2log2e)  w1: o-arg(-log2e)

        float eA = ex2_(aA); float sA = rcp_(1.0f + eA);  // sigmoid(i) / sigmoid(f)
        float eB = ex2_(aB); float rB = rcp_(1.0f + eB);  // g-partial / sigmoid(o)

        if (wid == 1 && j < H_) sfso[j] = make_float2(sA, rB);  // (sf, so)
        __syncthreads();   // barrier 1: gates f,o visible to wave0

        if (wid == 0) {
            float tg = __builtin_fmaf(-2.0f, rB, 1.0f);          // tanh(g)
            float2 t = sfso[j < H_ ? j : 0];                     // (sf, so)
            c = __builtin_fmaf(t.x, c, sA * tg);
            float ec = ex2_((2.0f * LOG2E) * c);
            float tc = __builtin_fmaf(-2.0f, rcp_(1.0f + ec), 1.0f);  // tanh(c)
            h = t.y * tc;
            int hn_ = __builtin_amdgcn_update_dpp(0, __builtin_bit_cast(int, h),
                                                  0xB1, 0xF, 0xF, true);
            unsigned hpk = __builtin_bit_cast(unsigned,
                __builtin_amdgcn_cvt_pkrtz(h, __builtin_bit_cast(float, hn_)));
            if ((j & 1) == 0 && j < H_) hs16[j >> 1] = hpk;
        }
        __syncthreads();   // barrier 2: new h visible to both waves

        #pragma unroll
        for (int m = 0; m < 25; ++m) hp[m] = hs16[m];
        xt = xt_n;
    }

    // outputs: [out (B,1)] [h_n (1,B,H)] [c_n (1,B,H)] concatenated
    if (wid == 0) {
        if (j < H_) {
            out[B_ + b * H_ + j]           = h;
            out[B_ + B_ * H_ + b * H_ + j] = c;
        }
        float p = (j < H_) ? h * fc_w[j] : 0.0f;
        #pragma unroll
        for (int off = 32; off > 0; off >>= 1) p += __shfl_xor(p, off);
        if (j == 0) out[b] = p + fc_b[0];
    }
}

extern "C" void kernel_launch(void* const* d_in, const int* in_sizes, int n_in,
                              void* d_out, int out_size, void* d_ws, size_t ws_size,
                              hipStream_t stream)
{
    const float* x    = (const float*)d_in[0];
    const float* h0   = (const float*)d_in[1];
    const float* c0   = (const float*)d_in[2];
    const float* W_ih = (const float*)d_in[3];
    const float* W_hh = (const float*)d_in[4];
    const float* b_ih = (const float*)d_in[5];
    const float* b_hh = (const float*)d_in[6];
    const float* fc_w = (const float*)d_in[7];
    const float* fc_b = (const float*)d_in[8];
    float* out = (float*)d_out;

    unsigned* wpk  = (unsigned*)d_ws;                               // 6400 u32 = 25.6 KB
    float* wih_pk  = (float*)((char*)d_ws + 6400 * 4);              // 256 f32
    float* bias_pk = (float*)((char*)d_ws + 6400 * 4 + 256 * 4);    // 256 f32

    lstm_pack<<<16, 256, 0, stream>>>(W_ih, W_hh, b_ih, b_hh, wpk, wih_pk, bias_pk);
    lstm_main<<<B_, 128, 0, stream>>>(x, h0, c0, fc_w, fc_b, wpk, wih_pk, bias_pk, out);
}

// Round 10
// 198.801 us; speedup vs baseline: 1.2288x; 1.2288x over previous
//
#include <hip/hip_runtime.h>

// LSTM forecast: B=1024, S=512, I=1, H=50.
// R10: ENTIRE 512-step recurrence in ONE hand-scheduled inline-asm block.
// R1-R9 (nine encodings: readlane/LDS/DPP broadcast, fdot2/fma/pk_fma,
// pinned/unpinned, 1-wave/2-wave) all land 195-260us with ~2x more VALU
// busy-cycles than the hand count -- compiler-invisible overhead. This pins
// the instruction stream exactly: per step 25 readlane + 25 mov + 100
// v_dot2_f32_f16 + 4 fma + ~23 activation ops + 2 pack, 4 gate chains
// round-robin, readlanes software-pipelined 6 slots ahead, x prefetched via
// SMEM s_load (SGPR offset), DPP/trans hazards hand-spaced.
// Weights: f16 pairs, per-lane contiguous (100 words @ lane base), loaded
// once into hard regs v80-v179. No LDS, no barriers, 1 wave = 1 batch.

typedef _Float16 half2v __attribute__((ext_vector_type(2)));

#define LOG2E 1.44269504088896340736f
#define B_ 1024
#define S_ 512
#define H_ 50

// Pack W_hh into per-lane-contiguous layout: wpk2[j*100 + g*25 + m] =
// f16pair(s*W_hh[g*50+j][2m], s*W_hh[g*50+j][2m+1]), s = -log2e (i,f,o),
// +2log2e (g). Zero-filled for lanes j>=50. Plus pre-scaled W_ih, biases.
__global__ void lstm_pack(const float* __restrict__ W_ih, const float* __restrict__ W_hh,
                          const float* __restrict__ b_ih, const float* __restrict__ b_hh,
                          unsigned* __restrict__ wpk2, float* __restrict__ wih_pk,
                          float* __restrict__ bias_pk)
{
    int tid = blockIdx.x * blockDim.x + threadIdx.x;
    int stride = blockDim.x * gridDim.x;
    for (int p = tid; p < 64 * 100; p += stride) {
        int j = p / 100;
        int r = p - j * 100;
        int g = r / 25;
        int m = r - g * 25;
        float s = (g == 2) ? (2.0f * LOG2E) : (-LOG2E);
        float a = 0.0f, bb = 0.0f;
        if (j < H_) {
            int row = g * H_ + j;
            a  = s * W_hh[row * H_ + 2 * m];
            bb = s * W_hh[row * H_ + 2 * m + 1];
        }
        half2v hv;
        hv.x = (_Float16)a;
        hv.y = (_Float16)bb;
        wpk2[p] = __builtin_bit_cast(unsigned, hv);
    }
    for (int p = tid; p < 4 * 64; p += stride) {
        int j = p & 63;
        int g = p >> 6;
        float s = (g == 2) ? (2.0f * LOG2E) : (-LOG2E);
        float wi = 0.0f, bb = 0.0f;
        if (j < H_) {
            int row = g * H_ + j;
            wi = s * W_ih[row];
            bb = s * (b_ih[row] + b_hh[row]);
        }
        wih_pk[p] = wi;
        bias_pk[p] = bb;
    }
}

__global__
__attribute__((amdgpu_flat_work_group_size(64, 64)))
__attribute__((amdgpu_waves_per_eu(1, 1)))
void lstm_main(const float* __restrict__ x, const float* __restrict__ h0,
               const float* __restrict__ c0, const float* __restrict__ fc_w,
               const float* __restrict__ fc_b, const unsigned* __restrict__ wpk2,
               const float* __restrict__ wih_pk, const float* __restrict__ bias_pk,
               float* __restrict__ out)
{
    const int b = blockIdx.x;
    const int j = threadIdx.x;

    float wih0 = wih_pk[0 * 64 + j], wih1 = wih_pk[1 * 64 + j];
    float wih2 = wih_pk[2 * 64 + j], wih3 = wih_pk[3 * 64 + j];
    float bs0 = bias_pk[0 * 64 + j], bs1 = bias_pk[1 * 64 + j];
    float bs2 = bias_pk[2 * 64 + j], bs3 = bias_pk[3 * 64 + j];

    float h = (j < H_) ? h0[b * H_ + j] : 0.0f;
    float c = (j < H_) ? c0[b * H_ + j] : 0.0f;

    // initial packed h-pairs (builtins, compile-proven R2-R9)
    int hn_ = __builtin_amdgcn_update_dpp(0, __builtin_bit_cast(int, h),
                                          0xB1, 0xF, 0xF, true);
    unsigned hpk0 = __builtin_bit_cast(unsigned,
        __builtin_amdgcn_cvt_pkrtz(h, __builtin_bit_cast(float, hn_)));

    unsigned long long wa = (unsigned long long)(wpk2 + (size_t)j * 100);
    const float* xrow = x + (size_t)b * S_;

    float hf, cf;
    asm volatile(
        // ---- state init ----
        "v_mov_b32 v60, %[hpk]\n\t"
        "v_mov_b32 v61, %[h]\n\t"
        "v_mov_b32 v62, %[c]\n\t"
        // ---- weights: 25 x dwordx4 into v80-v179 (per-lane contiguous) ----
        "global_load_dwordx4 v[80:83], %[wa], off\n\t"
        "global_load_dwordx4 v[84:87], %[wa], off offset:16\n\t"
        "global_load_dwordx4 v[88:91], %[wa], off offset:32\n\t"
        "global_load_dwordx4 v[92:95], %[wa], off offset:48\n\t"
        "global_load_dwordx4 v[96:99], %[wa], off offset:64\n\t"
        "global_load_dwordx4 v[100:103], %[wa], off offset:80\n\t"
        "global_load_dwordx4 v[104:107], %[wa], off offset:96\n\t"
        "global_load_dwordx4 v[108:111], %[wa], off offset:112\n\t"
        "global_load_dwordx4 v[112:115], %[wa], off offset:128\n\t"
        "global_load_dwordx4 v[116:119], %[wa], off offset:144\n\t"
        "global_load_dwordx4 v[120:123], %[wa], off offset:160\n\t"
        "global_load_dwordx4 v[124:127], %[wa], off offset:176\n\t"
        "global_load_dwordx4 v[128:131], %[wa], off offset:192\n\t"
        "global_load_dwordx4 v[132:135], %[wa], off offset:208\n\t"
        "global_load_dwordx4 v[136:139], %[wa], off offset:224\n\t"
        "global_load_dwordx4 v[140:143], %[wa], off offset:240\n\t"
        "global_load_dwordx4 v[144:147], %[wa], off offset:256\n\t"
        "global_load_dwordx4 v[148:151], %[wa], off offset:272\n\t"
        "global_load_dwordx4 v[152:155], %[wa], off offset:288\n\t"
        "global_load_dwordx4 v[156:159], %[wa], off offset:304\n\t"
        "global_load_dwordx4 v[160:163], %[wa], off offset:320\n\t"
        "global_load_dwordx4 v[164:167], %[wa], off offset:336\n\t"
        "global_load_dwordx4 v[168:171], %[wa], off offset:352\n\t"
        "global_load_dwordx4 v[172:175], %[wa], off offset:368\n\t"
        "global_load_dwordx4 v[176:179], %[wa], off offset:384\n\t"
        // ---- x prefetch: s21 = x[0] ----
        "s_mov_b32 s18, 0\n\t"
        "s_load_dword s17, %[xp], s18\n\t"
        "s_movk_i32 s16, 0x200\n\t"
        "s_waitcnt vmcnt(0) lgkmcnt(0)\n\t"
        "s_mov_b32 s21, s17\n\t"
        // ---- prologue readlanes (pairs 0-5) ----
        "v_readlane_b32 s24, v60, 0\n\t"
        "v_readlane_b32 s25, v60, 2\n\t"
        "v_readlane_b32 s26, v60, 4\n\t"
        "v_readlane_b32 s27, v60, 6\n\t"
        "v_readlane_b32 s28, v60, 8\n\t"
        "v_readlane_b32 s29, v60, 10\n\t"
        "Lstep_%=:\n\t"
        // prefetch next x (clamped to step 511)
        "s_add_u32 s18, s18, 4\n\t"
        "s_min_u32 s19, s18, 0x7FC\n\t"
        "s_load_dword s17, %[xp], s19\n\t"
        // acc init: a_g = xt*wih_g + bias_g
        "v_fma_f32 v64, s21, %[wih0], %[bs0]\n\t"
        "v_fma_f32 v65, s21, %[wih1], %[bs1]\n\t"
        "v_fma_f32 v66, s21, %[wih2], %[bs2]\n\t"
        "v_fma_f32 v67, s21, %[wih3], %[bs3]\n\t"
        "v_mov_b32 v40, s24\n\t"
        "v_mov_b32 v41, s25\n\t"
        "v_mov_b32 v42, s26\n\t"
        // ---- 25 slots: readlane (m+6) | mov (m+3) | 4 dots (m) ----
        "v_readlane_b32 s30, v60, 12\n\t"
        "v_mov_b32 v43, s27\n\t"
        "v_dot2_f32_f16 v64, v40, v80, v64\n\t"
        "v_dot2_f32_f16 v65, v40, v105, v65\n\t"
        "v_dot2_f32_f16 v66, v40, v130, v66\n\t"
        "v_dot2_f32_f16 v67, v40, v155, v67\n\t"
        "v_readlane_b32 s31, v60, 14\n\t"
        "v_mov_b32 v44, s28\n\t"
        "v_dot2_f32_f16 v64, v41, v81, v64\n\t"
        "v_dot2_f32_f16 v65, v41, v106, v65\n\t"
        "v_dot2_f32_f16 v66, v41, v131, v66\n\t"
        "v_dot2_f32_f16 v67, v41, v156, v67\n\t"
        "v_readlane_b32 s24, v60, 16\n\t"
        "v_mov_b32 v45, s29\n\t"
        "v_dot2_f32_f16 v64, v42, v82, v64\n\t"
        "v_dot2_f32_f16 v65, v42, v107, v65\n\t"
        "v_dot2_f32_f16 v66, v42, v132, v66\n\t"
        "v_dot2_f32_f16 v67, v42, v157, v67\n\t"
        "v_readlane_b32 s25, v60, 18\n\t"
        "v_mov_b32 v46, s30\n\t"
        "v_dot2_f32_f16 v64, v43, v83, v64\n\t"
        "v_dot2_f32_f16 v65, v43, v108, v65\n\t"
        "v_dot2_f32_f16 v66, v43, v133, v66\n\t"
        "v_dot2_f32_f16 v67, v43, v158, v67\n\t"
        "v_readlane_b32 s26, v60, 20\n\t"
        "v_mov_b32 v47, s31\n\t"
        "v_dot2_f32_f16 v64, v44, v84, v64\n\t"
        "v_dot2_f32_f16 v65, v44, v109, v65\n\t"
        "v_dot2_f32_f16 v66, v44, v134, v66\n\t"
        "v_dot2_f32_f16 v67, v44, v159, v67\n\t"
        "v_readlane_b32 s27, v60, 22\n\t"
        "v_mov_b32 v40, s24\n\t"
        "v_dot2_f32_f16 v64, v45, v85, v64\n\t"
        "v_dot2_f32_f16 v65, v45, v110, v65\n\t"
        "v_dot2_f32_f16 v66, v45, v135, v66\n\t"
        "v_dot2_f32_f16 v67, v45, v160, v67\n\t"
        "v_readlane_b32 s28, v60, 24\n\t"
        "v_mov_b32 v41, s25\n\t"
        "v_dot2_f32_f16 v64, v46, v86, v64\n\t"
        "v_dot2_f32_f16 v65, v46, v111, v65\n\t"
        "v_dot2_f32_f16 v66, v46, v136, v66\n\t"
        "v_dot2_f32_f16 v67, v46, v161, v67\n\t"
        "v_readlane_b32 s29, v60, 26\n\t"
        "v_mov_b32 v42, s26\n\t"
        "v_dot2_f32_f16 v64, v47, v87, v64\n\t"
        "v_dot2_f32_f16 v65, v47, v112, v65\n\t"
        "v_dot2_f32_f16 v66, v47, v137, v66\n\t"
        "v_dot2_f32_f16 v67, v47, v162, v67\n\t"
        "v_readlane_b32 s30, v60, 28\n\t"
        "v_mov_b32 v43, s27\n\t"
        "v_dot2_f32_f16 v64, v40, v88, v64\n\t"
        "v_dot2_f32_f16 v65, v40, v113, v65\n\t"
        "v_dot2_f32_f16 v66, v40, v138, v66\n\t"
        "v_dot2_f32_f16 v67, v40, v163, v67\n\t"
        "v_readlane_b32 s31, v60, 30\n\t"
        "v_mov_b32 v44, s28\n\t"
        "v_dot2_f32_f16 v64, v41, v89, v64\n\t"
        "v_dot2_f32_f16 v65, v41, v114, v65\n\t"
        "v_dot2_f32_f16 v66, v41, v139, v66\n\t"
        "v_dot2_f32_f16 v67, v41, v164, v67\n\t"
        "v_readlane_b32 s24, v60, 32\n\t"
        "v_mov_b32 v45, s29\n\t"
        "v_dot2_f32_f16 v64, v42, v90, v64\n\t"
        "v_dot2_f32_f16 v65, v42, v115, v65\n\t"
        "v_dot2_f32_f16 v66, v42, v140, v66\n\t"
        "v_dot2_f32_f16 v67, v42, v165, v67\n\t"
        "v_readlane_b32 s25, v60, 34\n\t"
        "v_mov_b32 v46, s30\n\t"
        "v_dot2_f32_f16 v64, v43, v91, v64\n\t"
        "v_dot2_f32_f16 v65, v43, v116, v65\n\t"
        "v_dot2_f32_f16 v66, v43, v141, v66\n\t"
        "v_dot2_f32_f16 v67, v43, v166, v67\n\t"
        "v_readlane_b32 s26, v60, 36\n\t"
        "v_mov_b32 v47, s31\n\t"
        "v_dot2_f32_f16 v64, v44, v92, v64\n\t"
        "v_dot2_f32_f16 v65, v44, v117, v65\n\t"
        "v_dot2_f32_f16 v66, v44, v142, v66\n\t"
        "v_dot2_f32_f16 v67, v44, v167, v67\n\t"
        "v_readlane_b32 s27, v60, 38\n\t"
        "v_mov_b32 v40, s24\n\t"
        "v_dot2_f32_f16 v64, v45, v93, v64\n\t"
        "v_dot2_f32_f16 v65, v45, v118, v65\n\t"
        "v_dot2_f32_f16 v66, v45, v143, v66\n\t"
        "v_dot2_f32_f16 v67, v45, v168, v67\n\t"
        "v_readlane_b32 s28, v60, 40\n\t"
        "v_mov_b32 v41, s25\n\t"
        "v_dot2_f32_f16 v64, v46, v94, v64\n\t"
        "v_dot2_f32_f16 v65, v46, v119, v65\n\t"
        "v_dot2_f32_f16 v66, v46, v144, v66\n\t"
        "v_dot2_f32_f16 v67, v46, v169, v67\n\t"
        "v_readlane_b32 s29, v60, 42\n\t"
        "v_mov_b32 v42, s26\n\t"
        "v_dot2_f32_f16 v64, v47, v95, v64\n\t"
        "v_dot2_f32_f16 v65, v47, v120, v65\n\t"
        "v_dot2_f32_f16 v66, v47, v145, v66\n\t"
        "v_dot2_f32_f16 v67, v47, v170, v67\n\t"
        "v_readlane_b32 s30, v60, 44\n\t"
        "v_mov_b32 v43, s27\n\t"
        "v_dot2_f32_f16 v64, v40, v96, v64\n\t"
        "v_dot2_f32_f16 v65, v40, v121, v65\n\t"
        "v_dot2_f32_f16 v66, v40, v146, v66\n\t"
        "v_dot2_f32_f16 v67, v40, v171, v67\n\t"
        "v_readlane_b32 s31, v60, 46\n\t"
        "v_mov_b32 v44, s28\n\t"
        "v_dot2_f32_f16 v64, v41, v97, v64\n\t"
        "v_dot2_f32_f16 v65, v41, v122, v65\n\t"
        "v_dot2_f32_f16 v66, v41, v147, v66\n\t"
        "v_dot2_f32_f16 v67, v41, v172, v67\n\t"
        "v_readlane_b32 s24, v60, 48\n\t"
        "v_mov_b32 v45, s29\n\t"
        "v_dot2_f32_f16 v64, v42, v98, v64\n\t"
        "v_dot2_f32_f16 v65, v42, v123, v65\n\t"
        "v_dot2_f32_f16 v66, v42, v148, v66\n\t"
        "v_dot2_f32_f16 v67, v42, v173, v67\n\t"
        "v_mov_b32 v46, s30\n\t"
        "v_dot2_f32_f16 v64, v43, v99, v64\n\t"
        "v_dot2_f32_f16 v65, v43, v124, v65\n\t"
        "v_dot2_f32_f16 v66, v43, v149, v66\n\t"
        "v_dot2_f32_f16 v67, v43, v174, v67\n\t"
        "v_mov_b32 v47, s31\n\t"
        "v_dot2_f32_f16 v64, v44, v100, v64\n\t"
        "v_dot2_f32_f16 v65, v44, v125, v65\n\t"
        "v_dot2_f32_f16 v66, v44, v150, v66\n\t"
        "v_dot2_f32_f16 v67, v44, v175, v67\n\t"
        "v_mov_b32 v40, s24\n\t"
        "v_dot2_f32_f16 v64, v45, v101, v64\n\t"
        "v_dot2_f32_f16 v65, v45, v126, v65\n\t"
        "v_dot2_f32_f16 v66, v45, v151, v66\n\t"
        "v_dot2_f32_f16 v67, v45, v176, v67\n\t"
        "v_dot2_f32_f16 v64, v46, v102, v64\n\t"
        "v_dot2_f32_f16 v65, v46, v127, v65\n\t"
        "v_dot2_f32_f16 v66, v46, v152, v66\n\t"
        "v_dot2_f32_f16 v67, v46, v177, v67\n\t"
        "v_dot2_f32_f16 v64, v47, v103, v64\n\t"
        "v_dot2_f32_f16 v65, v47, v128, v65\n\t"
        "v_dot2_f32_f16 v66, v47, v153, v66\n\t"
        "v_dot2_f32_f16 v67, v47, v178, v67\n\t"
        "v_dot2_f32_f16 v64, v40, v104, v64\n\t"
        "v_dot2_f32_f16 v65, v40, v129, v65\n\t"
        "v_dot2_f32_f16 v66, v40, v154, v66\n\t"
        "v_dot2_f32_f16 v67, v40, v179, v67\n\t"
        // ---- activations: i,f,g,o in v64..v67 (log2-scales pre-folded) ----
        "v_exp_f32 v68, v64\n\t"
        "v_exp_f32 v69, v65\n\t"
        "v_exp_f32 v70, v66\n\t"
        "v_exp_f32 v71, v67\n\t"
        "v_add_f32 v68, 1.0, v68\n\t"
        "v_add_f32 v69, 1.0, v69\n\t"
        "v_add_f32 v70, 1.0, v70\n\t"
        "v_add_f32 v71, 1.0, v71\n\t"
        "v_rcp_f32 v70, v70\n\t"
        "v_rcp_f32 v68, v68\n\t"
        "v_rcp_f32 v69, v69\n\t"
        "v_rcp_f32 v71, v71\n\t"
        "v_fma_f32 v72, -2.0, v70, 1.0\n\t"   // tanh(g)
        "v_mul_f32 v72, v68, v72\n\t"         // si*tg
        "v_fma_f32 v62, v69, v62, v72\n\t"    // c = sf*c + si*tg
        "v_mul_f32 v73, 0x4038aa3b, v62\n\t"  // 2*log2e*c
        "v_exp_f32 v73, v73\n\t"
        "s_nop 0\n\t"
        "v_add_f32 v73, 1.0, v73\n\t"
        "v_rcp_f32 v73, v73\n\t"
        "s_nop 0\n\t"
        "v_fma_f32 v73, -2.0, v73, 1.0\n\t"   // tanh(c)
        "v_mul_f32 v61, v71, v73\n\t"         // h = so*tanh(c)
        // ---- repack h pairs (DPP hazard buried under SALU) ----
        "s_waitcnt lgkmcnt(0)\n\t"
        "s_mov_b32 s21, s17\n\t"
        "v_mov_b32_dpp v63, v61 quad_perm:[1,0,3,2] row_mask:0xf bank_mask:0xf\n\t"
        "v_cvt_pkrtz_f16_f32 v60, v61, v63\n\t"
        // ---- next-iter readlanes for pairs 0-5 + loop ctl ----
        "s_sub_u32 s16, s16, 1\n\t"
        "v_readlane_b32 s24, v60, 0\n\t"
        "v_readlane_b32 s25, v60, 2\n\t"
        "v_readlane_b32 s26, v60, 4\n\t"
        "v_readlane_b32 s27, v60, 6\n\t"
        "v_readlane_b32 s28, v60, 8\n\t"
        "v_readlane_b32 s29, v60, 10\n\t"
        "s_cmp_lg_u32 s16, 0\n\t"
        "s_cbranch_scc1 Lstep_%=\n\t"
        "v_mov_b32 %[hf], v61\n\t"
        "v_mov_b32 %[cf], v62\n\t"
        : [hf] "=&v"(hf), [cf] "=&v"(cf)
        : [h] "v"(h), [c] "v"(c), [hpk] "v"(hpk0), [wa] "v"(wa),
          [xp] "s"(xrow),
          [wih0] "v"(wih0), [wih1] "v"(wih1), [wih2] "v"(wih2), [wih3] "v"(wih3),
          [bs0] "v"(bs0), [bs1] "v"(bs1), [bs2] "v"(bs2), [bs3] "v"(bs3)
        : "memory", "scc", "vcc",
          "s16", "s17", "s18", "s19", "s21",
          "s24", "s25", "s26", "s27", "s28", "s29", "s30", "s31",
          "v40", "v41", "v42", "v43", "v44", "v45", "v46", "v47",
          "v60", "v61", "v62", "v63", "v64", "v65", "v66", "v67",
          "v68", "v69", "v70", "v71", "v72", "v73",
          "v80", "v81", "v82", "v83", "v84", "v85", "v86", "v87",
          "v88", "v89", "v90", "v91", "v92", "v93", "v94", "v95",
          "v96", "v97", "v98", "v99", "v100", "v101", "v102", "v103",
          "v104", "v105", "v106", "v107", "v108", "v109", "v110", "v111",
          "v112", "v113", "v114", "v115", "v116", "v117", "v118", "v119",
          "v120", "v121", "v122", "v123", "v124", "v125", "v126", "v127",
          "v128", "v129", "v130", "v131", "v132", "v133", "v134", "v135",
          "v136", "v137", "v138", "v139", "v140", "v141", "v142", "v143",
          "v144", "v145", "v146", "v147", "v148", "v149", "v150", "v151",
          "v152", "v153", "v154", "v155", "v156", "v157", "v158", "v159",
          "v160", "v161", "v162", "v163", "v164", "v165", "v166", "v167",
          "v168", "v169", "v170", "v171", "v172", "v173", "v174", "v175",
          "v176", "v177", "v178", "v179");

    // outputs: [out (B,1)] [h_n (1,B,H)] [c_n (1,B,H)] concatenated
    if (j < H_) {
        out[B_ + b * H_ + j]           = hf;
        out[B_ + B_ * H_ + b * H_ + j] = cf;
    }
    float p = (j < H_) ? hf * fc_w[j] : 0.0f;
    #pragma unroll
    for (int off = 32; off > 0; off >>= 1) p += __shfl_xor(p, off);
    if (j == 0) out[b] = p + fc_b[0];
}

extern "C" void kernel_launch(void* const* d_in, const int* in_sizes, int n_in,
                              void* d_out, int out_size, void* d_ws, size_t ws_size,
                              hipStream_t stream)
{
    const float* x    = (const float*)d_in[0];
    const float* h0   = (const float*)d_in[1];
    const float* c0   = (const float*)d_in[2];
    const float* W_ih = (const float*)d_in[3];
    const float* W_hh = (const float*)d_in[4];
    const float* b_ih = (const float*)d_in[5];
    const float* b_hh = (const float*)d_in[6];
    const float* fc_w = (const float*)d_in[7];
    const float* fc_b = (const float*)d_in[8];
    float* out = (float*)d_out;

    unsigned* wpk2 = (unsigned*)d_ws;                               // 6400 u32 = 25.6 KB
    float* wih_pk  = (float*)((char*)d_ws + 6400 * 4);              // 256 f32
    float* bias_pk = (float*)((char*)d_ws + 6400 * 4 + 256 * 4);    // 256 f32

    lstm_pack<<<16, 256, 0, stream>>>(W_ih, W_hh, b_ih, b_hh, wpk2, wih_pk, bias_pk);
    lstm_main<<<B_, 64, 0, stream>>>(x, h0, c0, fc_w, fc_b, wpk2, wih_pk, bias_pk, out);
}